// Round 11
// baseline (344.893 us; speedup 1.0000x reference)
//
#include <hip/hip_runtime.h>
#include <hip/hip_bf16.h>

#define Bn 2
#define Tn 12
#define Hn 80
#define Wn 120
#define CIN 6
#define SITES (Hn * Wn)          // 9600
#define TILES 600                // 16-site flat tiles per field
#define NTILE (4 * TILES)        // 2400 tiles total
#define HSZ (4 * SITES * 32)     // 1228800 elements per state field
#define BLK 256

#define NA_D (48 * 64 * 8)       // gates operand-order B set, per dir
#define NB_D (24 * 64 * 8)       // candidate set per dir
#define NA (2 * NA_D)
#define NB (2 * NB_D)
#define NPX (Bn * Tn * SITES)
#define PREP_TOT (NA + NB + NPX) // 304128

typedef __attribute__((ext_vector_type(8))) short short8;
typedef __attribute__((ext_vector_type(4))) float f32x4;

__device__ __forceinline__ short f2bf(float f) {
    union { __hip_bfloat16 h; short s; } u;
    u.h = __float2bfloat16(f);
    return u.s;
}
__device__ __forceinline__ float bf2f(short s) {
    union { float f; unsigned u; } u;
    u.u = ((unsigned)(unsigned short)s) << 16;
    return u.f;
}
__device__ __forceinline__ float fast_sigmoid(float v) { return 1.f / (1.f + __expf(-v)); }
__device__ __forceinline__ float fast_tanh(float v) {
    v = fminf(fmaxf(v, -15.f), 15.f);
    float e = __expf(2.f * v);
    return (e - 1.f) / (e + 1.f);
}

// ---- prologue: expand weights to MFMA-operand order + pack x to padded bf16x8 ----
// bopA[dir][chunk12*4+nt][lane64][8]: chunk 0..2 = x (tap=chunk*4+q), 3..11 = h (tap=chunk-3)
// bopB[dir][chunk12*2+ntc][lane64][8]: same chunks, candidate cols
__global__ __launch_bounds__(BLK) void prep_kernel(
    const float* __restrict__ Wzr_f, const float* __restrict__ Wzr_b,
    const float* __restrict__ Wh_f,  const float* __restrict__ Wh_b,
    const float* __restrict__ Wx_f,  const float* __restrict__ Wx_b,
    const float* __restrict__ x,
    short* __restrict__ bopA, short* __restrict__ bopB, short* __restrict__ xb8)
{
    int i = blockIdx.x * BLK + threadIdx.x;
    if (i < NA) {
        int dir = i / NA_D; int r = i % NA_D;
        int f = r / 512; int lane = (r % 512) / 8; int j = r % 8;
        int q = lane >> 4, n = lane & 15;
        int chunk = f >> 2, nt = f & 3;
        float v = 0.f;
        if (chunk < 3) {
            int tap = chunk * 4 + q;
            if (tap < 9 && j < 6) v = (dir ? Wx_b : Wx_f)[(tap * CIN + j) * 96 + nt * 16 + n];
        } else {
            int tap = chunk - 3;
            v = (dir ? Wzr_b : Wzr_f)[(tap * 32 + q * 8 + j) * 64 + nt * 16 + n];
        }
        bopA[i] = f2bf(v);
    } else if (i < NA + NB) {
        int ii = i - NA;
        int dir = ii / NB_D; int r = ii % NB_D;
        int f = r / 512; int lane = (r % 512) / 8; int j = r % 8;
        int q = lane >> 4, n = lane & 15;
        int chunk = f >> 1, ntc = f & 1;
        float v = 0.f;
        if (chunk < 3) {
            int tap = chunk * 4 + q;
            if (tap < 9 && j < 6) v = (dir ? Wx_b : Wx_f)[(tap * CIN + j) * 96 + 64 + ntc * 16 + n];
        } else {
            int tap = chunk - 3;
            v = (dir ? Wh_b : Wh_f)[(tap * 32 + q * 8 + j) * 32 + ntc * 16 + n];
        }
        bopB[ii] = f2bf(v);
    } else if (i < PREP_TOT) {
        int p = i - NA - NB;
        const float* xp = x + (size_t)p * CIN;
        short v[8];
        #pragma unroll
        for (int c = 0; c < CIN; c++) v[c] = f2bf(xp[c]);
        v[6] = 0; v[7] = 0;
        *(short8*)&xb8[(size_t)p * 8] = *(short8*)v;
    }
}

// ---- gates: every tile computed exactly once; 4 independent waves/block ----
// grid 600 blocks x 256 thr; wave -> global tile bid*4+wid
__global__ __launch_bounds__(BLK) void gates_kernel(
    const short* __restrict__ xb8, const short* __restrict__ bopA,
    const float* __restrict__ b_f, const float* __restrict__ b_b,
    const short* __restrict__ hbp,     // bf16 h prev [field][site][32]
    float* __restrict__ zC,            // z fp32 C-layout [field*600+tt][nt2][lane][4]
    short* __restrict__ rh, int s)     // r*h bf16 [field][site][32]
{
    int tid = threadIdx.x, bid = blockIdx.x;
    int gtile = bid * 4 + (tid >> 6);
    int field = gtile / TILES, tt = gtile % TILES;
    int dir = field >> 1, b = field & 1;
    int t = dir ? (Tn - 1 - s) : s;

    int lane = tid & 63;
    int n = lane & 15, q = lane >> 4, q8 = q * 8;
    int site = tt * 16 + n;
    int y = site / Wn, px = site % Wn;

    const short* xs   = xb8 + (size_t)((b * Tn + t) * SITES) * 8;
    const short* hbpf = hbp + (size_t)field * SITES * 32;
    const short* bA   = bopA + dir * NA_D;
    const float* bias = dir ? b_b : b_f;

    f32x4 acc[4];
    #pragma unroll
    for (int nt = 0; nt < 4; nt++) acc[nt] = (f32x4)(bias[nt * 16 + n]);

    // x chunks (always)
    #pragma unroll
    for (int chunk = 0; chunk < 3; chunk++) {
        int tap = chunk * 4 + q;
        short8 a = (short8)(short)0;
        if (tap < 9) {
            int ay = y + tap / 3 - 1, ax = px + tap % 3 - 1;
            if (ay >= 0 && ay < Hn && ax >= 0 && ax < Wn)
                a = *(const short8*)&xs[(size_t)(ay * Wn + ax) * 8];
        }
        #pragma unroll
        for (int nt = 0; nt < 4; nt++) {
            short8 B = *(const short8*)&bA[((chunk * 4 + nt) * 64 + lane) * 8];
            acc[nt] = __builtin_amdgcn_mfma_f32_16x16x32_bf16(a, B, acc[nt], 0, 0, 0);
        }
    }
    // h chunks (9 taps)
    if (s > 0) {
        #pragma unroll
        for (int chunk = 3; chunk < 12; chunk++) {
            int tap = chunk - 3;
            int ay = y + tap / 3 - 1, ax = px + tap % 3 - 1;
            short8 a = (short8)(short)0;
            if (ay >= 0 && ay < Hn && ax >= 0 && ax < Wn)
                a = *(const short8*)&hbpf[(size_t)(ay * Wn + ax) * 32 + q8];
            #pragma unroll
            for (int nt = 0; nt < 4; nt++) {
                short8 B = *(const short8*)&bA[((chunk * 4 + nt) * 64 + lane) * 8];
                acc[nt] = __builtin_amdgcn_mfma_f32_16x16x32_bf16(a, B, acc[nt], 0, 0, 0);
            }
        }
    }

    // epilogue: z -> zC (C-layout vector), r*h(bf16) -> rh (site layout)
    short* rhs = rh + (size_t)field * SITES * 32;
    #pragma unroll
    for (int nt = 0; nt < 4; nt++) {
        if (nt < 2) {
            f32x4 z;
            #pragma unroll
            for (int r = 0; r < 4; r++) z[r] = fast_sigmoid(acc[nt][r]);
            *(f32x4*)&zC[((size_t)gtile * 2 + nt) * 256 + lane * 4] = z;
        } else {
            int ch = (nt - 2) * 16 + n;
            #pragma unroll
            for (int r = 0; r < 4; r++) {
                int site_e = tt * 16 + q * 4 + r;
                float rhv = 0.f;
                if (s > 0)
                    rhv = fast_sigmoid(acc[nt][r]) * bf2f(hbpf[(size_t)site_e * 32 + ch]);
                rhs[(size_t)site_e * 32 + ch] = f2bf(rhv);
            }
        }
    }
}

// ---- update: candidate conv over rh, then h = z*h_prev + (1-z)*tanh(.) ----
__global__ __launch_bounds__(BLK) void update_kernel(
    const short* __restrict__ xb8, const short* __restrict__ bopB,
    const float* __restrict__ b_f, const float* __restrict__ b_b,
    const short* __restrict__ rh, const float* __restrict__ zC,
    const float* __restrict__ hfCp, float* __restrict__ hfCc,
    short* __restrict__ hbc, float* __restrict__ out, int s)
{
    int tid = threadIdx.x, bid = blockIdx.x;
    int gtile = bid * 4 + (tid >> 6);
    int field = gtile / TILES, tt = gtile % TILES;
    int dir = field >> 1, b = field & 1;
    int t = dir ? (Tn - 1 - s) : s;

    int lane = tid & 63;
    int n = lane & 15, q = lane >> 4, q8 = q * 8;
    int site = tt * 16 + n;
    int y = site / Wn, px = site % Wn;

    const short* xs  = xb8 + (size_t)((b * Tn + t) * SITES) * 8;
    const short* rhs = rh + (size_t)field * SITES * 32;
    const short* bB  = bopB + dir * NB_D;
    const float* bias = dir ? b_b : b_f;

    f32x4 acc2[2];
    #pragma unroll
    for (int ntc = 0; ntc < 2; ntc++) acc2[ntc] = (f32x4)(bias[64 + ntc * 16 + n]);

    // x chunks
    #pragma unroll
    for (int chunk = 0; chunk < 3; chunk++) {
        int tap = chunk * 4 + q;
        short8 a = (short8)(short)0;
        if (tap < 9) {
            int ay = y + tap / 3 - 1, ax = px + tap % 3 - 1;
            if (ay >= 0 && ay < Hn && ax >= 0 && ax < Wn)
                a = *(const short8*)&xs[(size_t)(ay * Wn + ax) * 8];
        }
        #pragma unroll
        for (int ntc = 0; ntc < 2; ntc++) {
            short8 B = *(const short8*)&bB[((chunk * 2 + ntc) * 64 + lane) * 8];
            acc2[ntc] = __builtin_amdgcn_mfma_f32_16x16x32_bf16(a, B, acc2[ntc], 0, 0, 0);
        }
    }
    // rh chunks (9-tap gather; rh fully written by gates this step)
    #pragma unroll
    for (int chunk = 3; chunk < 12; chunk++) {
        int tap = chunk - 3;
        int ay = y + tap / 3 - 1, ax = px + tap % 3 - 1;
        short8 a = (short8)(short)0;
        if (ay >= 0 && ay < Hn && ax >= 0 && ax < Wn)
            a = *(const short8*)&rhs[(size_t)(ay * Wn + ax) * 32 + q8];
        #pragma unroll
        for (int ntc = 0; ntc < 2; ntc++) {
            short8 B = *(const short8*)&bB[((chunk * 2 + ntc) * 64 + lane) * 8];
            acc2[ntc] = __builtin_amdgcn_mfma_f32_16x16x32_bf16(a, B, acc2[ntc], 0, 0, 0);
        }
    }

    // epilogue
    short* hbcf = hbc + (size_t)field * SITES * 32;
    #pragma unroll
    for (int ntc = 0; ntc < 2; ntc++) {
        size_t cofs = ((size_t)gtile * 2 + ntc) * 256 + lane * 4;
        f32x4 z = *(const f32x4*)&zC[cofs];
        f32x4 hp = (f32x4)0.f;
        if (s > 0) hp = *(const f32x4*)&hfCp[cofs];
        f32x4 hn;
        #pragma unroll
        for (int r = 0; r < 4; r++) {
            float hh = fast_tanh(acc2[ntc][r]);
            hn[r] = z[r] * hp[r] + (1.f - z[r]) * hh;
        }
        *(f32x4*)&hfCc[cofs] = hn;
        int ch = ntc * 16 + n;
        #pragma unroll
        for (int r = 0; r < 4; r++) {
            int site_e = tt * 16 + q * 4 + r;        // flat tiles cover all 9600 sites exactly
            hbcf[(size_t)site_e * 32 + ch] = f2bf(hn[r]);
            __builtin_nontemporal_store(hn[r],
                &out[((size_t)((b * Tn + t) * SITES) + site_e) * 64 + dir * 32 + ch]);
        }
    }
}

extern "C" void kernel_launch(void* const* d_in, const int* in_sizes, int n_in,
                              void* d_out, int out_size, void* d_ws, size_t ws_size,
                              hipStream_t stream)
{
    const float* x     = (const float*)d_in[0];
    const float* Wx_f  = (const float*)d_in[1];
    const float* b_f   = (const float*)d_in[2];
    const float* Wzr_f = (const float*)d_in[3];
    const float* Wh_f  = (const float*)d_in[4];
    const float* Wx_b  = (const float*)d_in[5];
    const float* b_b   = (const float*)d_in[6];
    const float* Wzr_b = (const float*)d_in[7];
    const float* Wh_b  = (const float*)d_in[8];
    float* out = (float*)d_out;

    char* w = (char*)d_ws;
    short* hb0  = (short*)w;  w += (size_t)HSZ * 2;   // bf16 h state ping-pong
    short* hb1  = (short*)w;  w += (size_t)HSZ * 2;
    float* hfC0 = (float*)w;  w += (size_t)HSZ * 4;   // fp32 h state (C-layout) ping-pong
    float* hfC1 = (float*)w;  w += (size_t)HSZ * 4;
    float* zC   = (float*)w;  w += (size_t)HSZ * 4;   // z gate (C-layout)
    short* rh   = (short*)w;  w += (size_t)HSZ * 2;   // r*h (site layout)
    short* xb8  = (short*)w;  w += (size_t)NPX * 8 * 2;
    short* bopA = (short*)w;  w += (size_t)NA * 2;
    short* bopB = (short*)w;  w += (size_t)NB * 2;
    // total ~26 MB

    prep_kernel<<<(PREP_TOT + BLK - 1) / BLK, BLK, 0, stream>>>(
        Wzr_f, Wzr_b, Wh_f, Wh_b, Wx_f, Wx_b, x, bopA, bopB, xb8);

    for (int s = 0; s < Tn; s++) {
        const short* hbp = (s & 1) ? hb0 : hb1;
        short*       hbc = (s & 1) ? hb1 : hb0;
        const float* hfp = (s & 1) ? hfC0 : hfC1;
        float*       hfc = (s & 1) ? hfC1 : hfC0;
        gates_kernel<<<NTILE / 4, BLK, 0, stream>>>(xb8, bopA, b_f, b_b, hbp, zC, rh, s);
        update_kernel<<<NTILE / 4, BLK, 0, stream>>>(xb8, bopB, b_f, b_b, rh, zC,
                                                     hfp, hfc, hbc, out, s);
    }
}